// Round 1
// baseline (536.794 us; speedup 1.0000x reference)
//
#include <hip/hip_runtime.h>
#include <hip/hip_bf16.h>
#include <math.h>

#define N_NODES 100000
#define N_EDGES 3200000
#define D_IN 256
#define H1 16
#define H2 32
#define ROWS 32   // rows per block in the x@W1 kernel

// ---------------- zero workspace region ----------------
__global__ void k_zero(float4* __restrict__ p, int n4) {
    int i = blockIdx.x * blockDim.x + threadIdx.x;
    if (i < n4) p[i] = make_float4(0.f, 0.f, 0.f, 0.f);
}

// ---------------- t = x @ W1  [N,256]@[256,16] ----------------
// Block = 256 threads, 32 rows per block. x tile staged in LDS (padded to
// 260 floats/row: r0 stride maps to 4 distinct banks -> conflict-free with
// 16-lane broadcast). W1 staged in LDS [k*16+f] -> 16 distinct banks.
__global__ __launch_bounds__(256) void k_xw1(const float* __restrict__ x,
                                             const float* __restrict__ W1,
                                             float* __restrict__ t,
                                             int n_nodes) {
    __shared__ float xs[ROWS][D_IN + 4];
    __shared__ float w1s[D_IN * H1];
    const int tid = threadIdx.x;

    // load W1: 4096 floats = 1024 float4
    {
        const float4* src = (const float4*)W1;
        float4* dst = (float4*)w1s;
        for (int i = tid; i < D_IN * H1 / 4; i += 256) dst[i] = src[i];
    }
    // load x tile: 32*256 floats = 2048 float4, coalesced
    const int row0 = blockIdx.x * ROWS;
    for (int i = tid; i < ROWS * D_IN / 4; i += 256) {
        int r  = i >> 6;          // 64 float4 per row
        int kc = i & 63;
        int grow = row0 + r;
        float4 v = (grow < n_nodes) ? ((const float4*)x)[grow * (D_IN / 4) + kc]
                                    : make_float4(0.f, 0.f, 0.f, 0.f);
        *(float4*)&xs[r][kc * 4] = v;
    }
    __syncthreads();

    const int f  = tid & 15;
    const int r0 = tid >> 4;      // 0..15 -> rows r0 and r0+16
    float acc0 = 0.f, acc1 = 0.f;
    const float* xr0 = &xs[r0][0];
    const float* xr1 = &xs[r0 + 16][0];
#pragma unroll 8
    for (int k = 0; k < D_IN; k++) {
        float w = w1s[k * H1 + f];
        acc0 = fmaf(xr0[k], w, acc0);
        acc1 = fmaf(xr1[k], w, acc1);
    }
    int gr0 = row0 + r0, gr1 = row0 + r0 + 16;
    if (gr0 < n_nodes) t[gr0 * H1 + f] = acc0;   // 256B coalesced per wave
    if (gr1 < n_nodes) t[gr1 * H1 + f] = acc1;
}

// ---------------- edge pass: g[r] += val * t[c];  colsum[c] += val --------
// 16 lanes per edge (one per feature). Gather t[c*16+f] is one 64B request
// per edge group; scatter is 16 fp32 atomics into one cacheline.
__global__ __launch_bounds__(256) void k_edge(const int* __restrict__ rows,
                                              const int* __restrict__ cols,
                                              const float* __restrict__ vals,
                                              const float* __restrict__ t,
                                              float* __restrict__ g,
                                              float* __restrict__ colsum,
                                              int E) {
    int tid = blockIdx.x * 256 + threadIdx.x;
    int e = tid >> 4;
    int f = tid & 15;
    if (e >= E) return;
    int r = rows[e];
    int c = cols[e];
    float v = vals[e];
    float tv = t[c * H1 + f];
    atomicAdd(&g[r * H1 + f], v * tv);
    if (f == 0) atomicAdd(&colsum[c], v);
}

// ---------------- s[f] = sum_j colsum[j] * relu(g[j][f]) ----------------
__global__ __launch_bounds__(256) void k_s(const float* __restrict__ g,
                                           const float* __restrict__ colsum,
                                           float* __restrict__ s,
                                           int n_nodes) {
    const int f = threadIdx.x & 15;
    int grp  = (blockIdx.x * 256 + threadIdx.x) >> 4;
    int ngrp = (gridDim.x * 256) >> 4;
    float acc = 0.f;
    for (int j = grp; j < n_nodes; j += ngrp) {
        float cv = colsum[j];
        float gv = g[j * H1 + f];
        acc = fmaf(cv, fmaxf(gv, 0.f), acc);
    }
    // reduce the 4 node-subgroups within the wave (lanes l, l^16, l^32)
    acc += __shfl_xor(acc, 16, 64);
    acc += __shfl_xor(acc, 32, 64);
    __shared__ float red[4][16];
    int lane = threadIdx.x & 63, wid = threadIdx.x >> 6;
    if (lane < 16) red[wid][lane] = acc;
    __syncthreads();
    if (threadIdx.x < 16) {
        float v = red[0][threadIdx.x] + red[1][threadIdx.x] +
                  red[2][threadIdx.x] + red[3][threadIdx.x];
        atomicAdd(&s[threadIdx.x], v);
    }
}

// ---------------- out = sigmoid((s @ W2) @ w_out + b_out) ----------------
__global__ void k_out(const float* __restrict__ s, const float* __restrict__ W2,
                      const float* __restrict__ w_out,
                      const float* __restrict__ b_out,
                      float* __restrict__ out) {
    int f2 = threadIdx.x;   // 64 threads, 32 active
    float m = 0.f;
    if (f2 < H2) {
        float v = 0.f;
#pragma unroll
        for (int f1 = 0; f1 < H1; f1++) v = fmaf(s[f1], W2[f1 * H2 + f2], v);
        m = v * w_out[f2];
    }
    for (int off = 32; off; off >>= 1) m += __shfl_down(m, off, 64);
    if (f2 == 0) out[0] = 1.f / (1.f + expf(-(m + b_out[0])));
}

extern "C" void kernel_launch(void* const* d_in, const int* in_sizes, int n_in,
                              void* d_out, int out_size, void* d_ws, size_t ws_size,
                              hipStream_t stream) {
    const float* x         = (const float*)d_in[0];
    const float* edge_vals = (const float*)d_in[1];
    const float* W1        = (const float*)d_in[2];
    const float* W2        = (const float*)d_in[3];
    const float* w_out     = (const float*)d_in[4];
    const float* b_out     = (const float*)d_in[5];
    const int*   edge_rows = (const int*)d_in[6];
    const int*   edge_cols = (const int*)d_in[7];
    float* out = (float*)d_out;

    const int N = N_NODES;
    const int E = in_sizes[1];   // 3.2M

    // workspace layout (bytes):
    //   t:      [0,            6,400,000)   N*16 fp32
    //   g:      [6,400,000,   12,800,000)   N*16 fp32  (zeroed)
    //   colsum: [12,800,000,  13,200,000)   N fp32     (zeroed)
    //   s:      [13,200,000,  13,200,064)   16 fp32    (zeroed)
    char* ws = (char*)d_ws;
    float* t      = (float*)(ws);
    float* g      = (float*)(ws + 6400000);
    float* colsum = (float*)(ws + 12800000);
    float* s      = (float*)(ws + 13200000);

    // zero g + colsum + s: 6,800,064 B = 425,004 float4
    const int n4 = 425004;
    k_zero<<<(n4 + 255) / 256, 256, 0, stream>>>((float4*)g, n4);

    k_xw1<<<(N + ROWS - 1) / ROWS, 256, 0, stream>>>(x, W1, t, N);

    int edge_threads = E * 16;
    k_edge<<<(edge_threads + 255) / 256, 256, 0, stream>>>(
        edge_rows, edge_cols, edge_vals, t, g, colsum, E);

    k_s<<<1024, 256, 0, stream>>>(g, colsum, s, N);

    k_out<<<1, 64, 0, stream>>>(s, W2, w_out, b_out, out);
}